// Round 1
// baseline (2149.399 us; speedup 1.0000x reference)
//
#include <hip/hip_runtime.h>
#include <stdint.h>

#define T_TOK 8192
#define H_DIM 2048
#define I_DIM 4096
#define E_NUM 8
#define SCAP (2*T_TOK + E_NUM*128)   // 17408 padded slot capacity

typedef short bf16x8 __attribute__((ext_vector_type(8)));
typedef float f32x4  __attribute__((ext_vector_type(4)));

typedef __attribute__((address_space(1))) void gvoid;
typedef __attribute__((address_space(3))) void svoid;

__device__ __forceinline__ void gl_lds16(const void* g, void* l) {
    // async global->LDS, 16B/lane; LDS dest = wave-uniform base + lane*16
    __builtin_amdgcn_global_load_lds((gvoid*)g, (svoid*)l, 16, 0, 0);
}

__device__ __forceinline__ unsigned short f2bf(float f) {
    union { float f; unsigned int u; } v; v.f = f;
    unsigned int u = v.u;
    unsigned int r = (u + 0x7fffu + ((u >> 16) & 1u)) >> 16;  // RNE
    return (unsigned short)r;
}

// ---- ws layout (bytes) ----
// hdr ints: [0..7]=counts [16..23]=cursors [32..40]=off[9] [48]=total
#define WS_ROWS   4096ULL
#define WS_SLOTW  (WS_ROWS + (unsigned long long)SCAP*4)
#define WS_TOKE   (WS_SLOTW + (unsigned long long)SCAP*4)
#define WS_TOKW   (WS_TOKE + 2ULL*T_TOK*4)
#define OFF_XBF   1048576ULL
#define OFF_W13   (OFF_XBF + 2ULL*T_TOK*H_DIM)
#define OFF_W2    (OFF_W13 + 2ULL*E_NUM*2*I_DIM*H_DIM)
#define OFF_ACT   (OFF_W2  + 2ULL*E_NUM*H_DIM*I_DIM)

struct us4 { unsigned short x, y, z, w; };

__global__ void k_init(int* hdr) {
    int i = threadIdx.x;
    if (i < 64) hdr[i] = 0;
}

__global__ void k_zero(float4* out, long n4) {
    long i = (long)blockIdx.x * blockDim.x + threadIdx.x;
    if (i < n4) out[i] = make_float4(0.f, 0.f, 0.f, 0.f);
}

__global__ void k_cvt(const float4* __restrict__ in, us4* __restrict__ out, long n4) {
    long i = (long)blockIdx.x * blockDim.x + threadIdx.x;
    if (i >= n4) return;
    float4 v = in[i];
    us4 o; o.x = f2bf(v.x); o.y = f2bf(v.y); o.z = f2bf(v.z); o.w = f2bf(v.w);
    out[i] = o;
}

__global__ void k_router(const float* __restrict__ logits, int* __restrict__ hdr,
                         int* __restrict__ tok_e, float* __restrict__ tok_w) {
    int t = blockIdx.x * blockDim.x + threadIdx.x;
    if (t >= T_TOK) return;
    float l[E_NUM];
    #pragma unroll
    for (int e = 0; e < E_NUM; e++) l[e] = logits[t * E_NUM + e];
    int i0 = 0; float m0 = l[0];
    #pragma unroll
    for (int e = 1; e < E_NUM; e++) if (l[e] > m0) { m0 = l[e]; i0 = e; }
    int i1 = -1; float m1 = -1e30f;
    #pragma unroll
    for (int e = 0; e < E_NUM; e++) if (e != i0 && l[e] > m1) { m1 = l[e]; i1 = e; }
    // normalized top-2 softmax weights == softmax over the two logits
    float p1 = expf(m1 - m0);
    float w0 = 1.f / (1.f + p1);
    float w1 = p1 * w0;
    tok_e[2*t] = i0; tok_e[2*t+1] = i1;
    tok_w[2*t] = w0; tok_w[2*t+1] = w1;
    atomicAdd(&hdr[i0], 1);
    atomicAdd(&hdr[i1], 1);
}

__global__ void k_offsets(int* hdr, int* slot_rows, float* slot_w) {
    if (threadIdx.x == 0) {
        int acc = 0;
        for (int e = 0; e < E_NUM; e++) {
            hdr[32 + e] = acc;
            int c = hdr[e];
            acc += (c + 127) & ~127;   // pad each expert region to 128 rows
        }
        hdr[32 + E_NUM] = acc;
        hdr[48] = acc;
    }
    for (int i = threadIdx.x; i < SCAP; i += blockDim.x) { slot_rows[i] = 0; slot_w[i] = 0.f; }
}

__global__ void k_place(const int* __restrict__ tok_e, const float* __restrict__ tok_w,
                        int* hdr, int* slot_rows, float* slot_w) {
    int t = blockIdx.x * blockDim.x + threadIdx.x;
    if (t >= T_TOK) return;
    #pragma unroll
    for (int k = 0; k < 2; k++) {
        int e = tok_e[2*t + k];
        float w = tok_w[2*t + k];
        int pos = atomicAdd(&hdr[16 + e], 1);
        int slot = hdr[32 + e] + pos;
        slot_rows[slot] = t;
        slot_w[slot] = w;
    }
}

// GEMM1: act[slot, i] = silu(x@w13g^T) * (x@w13u^T), bf16 out. 128x128 tile, BK=32.
// Double-buffered LDS: stage k+1 into buf^1 BEFORE compute on buf; ONE barrier/K-step.
__global__ __launch_bounds__(256, 2)
void k_gemm1(const unsigned short* __restrict__ xbf,
             const unsigned short* __restrict__ w13,
             const int* __restrict__ slot_rows,
             const int* __restrict__ hdr,
             unsigned short* __restrict__ act) {
    const int total = hdr[48];
    const int row0 = blockIdx.y * 128;
    if (row0 >= total) return;
    int e = 0;
    #pragma unroll
    for (int q = 0; q < E_NUM - 1; q++) if (row0 >= hdr[32 + q + 1]) e = q + 1;
    const int cb = blockIdx.x;   // 0..31 over gate columns (I/128)

    // 2 buffers x (A | G | U), each 128x32 bf16 = 8KB -> 48KB total
    __shared__ __align__(16) unsigned short lds[2 * 3 * 128 * 32];

    const int tid = threadIdx.x;
    const int wave = tid >> 6, lane = tid & 63;
    const int srow = lane >> 2, scol = (lane & 3) * 8;

    const unsigned short* aP[2]; const unsigned short* gP[2]; const unsigned short* uP[2];
    int lo[2];
    #pragma unroll
    for (int c = 0; c < 2; c++) {
        int r = c * 64 + wave * 16 + srow;          // 0..127 tile row
        int tok = slot_rows[row0 + r];
        aP[c] = xbf + (size_t)tok * H_DIM + scol;
        size_t n = (size_t)(cb * 128 + r);
        gP[c] = w13 + ((size_t)e * 2 * I_DIM + n) * H_DIM + scol;
        uP[c] = w13 + ((size_t)e * 2 * I_DIM + I_DIM + n) * H_DIM + scol;
        lo[c] = (c * 64 + wave * 16) * 32;          // wave-uniform LDS row offset (elems)
    }

    const int wm = wave >> 1, wn = wave & 1;
    const int fm = lane & 15, fk = (lane >> 4) * 8;

    f32x4 accg[4][4], accu[4][4];
    f32x4 zero = {0.f, 0.f, 0.f, 0.f};
    #pragma unroll
    for (int i = 0; i < 4; i++)
        #pragma unroll
        for (int j = 0; j < 4; j++) { accg[i][j] = zero; accu[i][j] = zero; }

#define G1_STAGE(BUF, KO) do {                                   \
        unsigned short* _p = lds + (BUF) * 12288;                \
        _Pragma("unroll")                                        \
        for (int c = 0; c < 2; c++) {                            \
            gl_lds16(aP[c] + (KO), _p + lo[c]);                  \
            gl_lds16(gP[c] + (KO), _p + 4096 + lo[c]);           \
            gl_lds16(uP[c] + (KO), _p + 8192 + lo[c]);           \
        }                                                        \
    } while (0)

    G1_STAGE(0, 0);
    __syncthreads();              // drains vmcnt -> buf0 ready
    int cur = 0;

    for (int k0 = 0; k0 < H_DIM; k0 += 32) {
        if (k0 + 32 < H_DIM) G1_STAGE(cur ^ 1, k0 + 32);   // prefetch overlaps compute

        const unsigned short* ldsA = lds + cur * 12288;
        const unsigned short* ldsG = ldsA + 4096;
        const unsigned short* ldsU = ldsA + 8192;

        bf16x8 a[4], bg[4], bu[4];
        #pragma unroll
        for (int i = 0; i < 4; i++) a[i] = *(const bf16x8*)&ldsA[(wm * 64 + i * 16 + fm) * 32 + fk];
        #pragma unroll
        for (int j = 0; j < 4; j++) {
            bg[j] = *(const bf16x8*)&ldsG[(wn * 64 + j * 16 + fm) * 32 + fk];
            bu[j] = *(const bf16x8*)&ldsU[(wn * 64 + j * 16 + fm) * 32 + fk];
        }
        #pragma unroll
        for (int i = 0; i < 4; i++)
            #pragma unroll
            for (int j = 0; j < 4; j++) {
                accg[i][j] = __builtin_amdgcn_mfma_f32_16x16x32_bf16(a[i], bg[j], accg[i][j], 0, 0, 0);
                accu[i][j] = __builtin_amdgcn_mfma_f32_16x16x32_bf16(a[i], bu[j], accu[i][j], 0, 0, 0);
            }

        __syncthreads();          // drains lgkmcnt (reads done) + vmcnt (prefetch landed)
        cur ^= 1;
    }
#undef G1_STAGE

    const int r4 = (lane >> 4) * 4;
    #pragma unroll
    for (int i = 0; i < 4; i++) {
        #pragma unroll
        for (int j = 0; j < 4; j++) {
            int col = cb * 128 + wn * 64 + j * 16 + fm;
            #pragma unroll
            for (int r = 0; r < 4; r++) {
                int slot = row0 + wm * 64 + i * 16 + r4 + r;
                float g = accg[i][j][r], u = accu[i][j][r];
                float s = g / (1.f + __expf(-g)) * u;   // silu(g)*u
                act[(size_t)slot * I_DIM + col] = f2bf(s);
            }
        }
    }
}

// GEMM2: y = act @ w2^T, scatter out[token] += w * y via atomics.
// Same double-buffered single-barrier schedule.
__global__ __launch_bounds__(256, 2)
void k_gemm2(const unsigned short* __restrict__ act,
             const unsigned short* __restrict__ w2,
             const int* __restrict__ slot_rows,
             const float* __restrict__ slot_w,
             const int* __restrict__ hdr,
             float* __restrict__ out) {
    const int total = hdr[48];
    const int row0 = blockIdx.y * 128;
    if (row0 >= total) return;
    int e = 0;
    #pragma unroll
    for (int q = 0; q < E_NUM - 1; q++) if (row0 >= hdr[32 + q + 1]) e = q + 1;
    const int cb = blockIdx.x;   // 0..15 over H/128

    // 2 buffers x (A | B), each 128x32 bf16 = 8KB -> 32KB total
    __shared__ __align__(16) unsigned short lds[2 * 2 * 128 * 32];

    const int tid = threadIdx.x;
    const int wave = tid >> 6, lane = tid & 63;
    const int srow = lane >> 2, scol = (lane & 3) * 8;

    const unsigned short* aP[2]; const unsigned short* bP[2];
    int lo[2];
    #pragma unroll
    for (int c = 0; c < 2; c++) {
        int r = c * 64 + wave * 16 + srow;
        aP[c] = act + (size_t)(row0 + r) * I_DIM + scol;
        size_t n = (size_t)(cb * 128 + r);
        bP[c] = w2 + ((size_t)e * H_DIM + n) * I_DIM + scol;
        lo[c] = (c * 64 + wave * 16) * 32;
    }

    const int wm = wave >> 1, wn = wave & 1;
    const int fm = lane & 15, fk = (lane >> 4) * 8;

    f32x4 acc[4][4];
    f32x4 zero = {0.f, 0.f, 0.f, 0.f};
    #pragma unroll
    for (int i = 0; i < 4; i++)
        #pragma unroll
        for (int j = 0; j < 4; j++) acc[i][j] = zero;

#define G2_STAGE(BUF, KO) do {                                   \
        unsigned short* _p = lds + (BUF) * 8192;                 \
        _Pragma("unroll")                                        \
        for (int c = 0; c < 2; c++) {                            \
            gl_lds16(aP[c] + (KO), _p + lo[c]);                  \
            gl_lds16(bP[c] + (KO), _p + 4096 + lo[c]);           \
        }                                                        \
    } while (0)

    G2_STAGE(0, 0);
    __syncthreads();
    int cur = 0;

    for (int k0 = 0; k0 < I_DIM; k0 += 32) {
        if (k0 + 32 < I_DIM) G2_STAGE(cur ^ 1, k0 + 32);

        const unsigned short* ldsA = lds + cur * 8192;
        const unsigned short* ldsB = ldsA + 4096;

        bf16x8 a[4], b[4];
        #pragma unroll
        for (int i = 0; i < 4; i++) a[i] = *(const bf16x8*)&ldsA[(wm * 64 + i * 16 + fm) * 32 + fk];
        #pragma unroll
        for (int j = 0; j < 4; j++) b[j] = *(const bf16x8*)&ldsB[(wn * 64 + j * 16 + fm) * 32 + fk];
        #pragma unroll
        for (int i = 0; i < 4; i++)
            #pragma unroll
            for (int j = 0; j < 4; j++)
                acc[i][j] = __builtin_amdgcn_mfma_f32_16x16x32_bf16(a[i], b[j], acc[i][j], 0, 0, 0);

        __syncthreads();
        cur ^= 1;
    }
#undef G2_STAGE

    const int r4 = (lane >> 4) * 4;
    int toks[16]; float ww[16];
    #pragma unroll
    for (int i = 0; i < 4; i++)
        #pragma unroll
        for (int r = 0; r < 4; r++) {
            int slot = row0 + wm * 64 + i * 16 + r4 + r;
            toks[i * 4 + r] = slot_rows[slot];
            ww[i * 4 + r] = slot_w[slot];
        }
    #pragma unroll
    for (int i = 0; i < 4; i++) {
        #pragma unroll
        for (int j = 0; j < 4; j++) {
            int col = cb * 128 + wn * 64 + j * 16 + fm;
            #pragma unroll
            for (int r = 0; r < 4; r++) {
                float v = ww[i * 4 + r] * acc[i][j][r];
                atomicAdd(&out[(size_t)toks[i * 4 + r] * H_DIM + col], v);
            }
        }
    }
}

extern "C" void kernel_launch(void* const* d_in, const int* in_sizes, int n_in,
                              void* d_out, int out_size, void* d_ws, size_t ws_size,
                              hipStream_t stream) {
    const float* x      = (const float*)d_in[0];
    const float* logits = (const float*)d_in[1];
    const float* w13    = (const float*)d_in[2];
    const float* w2     = (const float*)d_in[3];
    float* out = (float*)d_out;
    char* ws = (char*)d_ws;

    int*   hdr       = (int*)ws;
    int*   slot_rows = (int*)(ws + WS_ROWS);
    float* slot_w    = (float*)(ws + WS_SLOTW);
    int*   tok_e     = (int*)(ws + WS_TOKE);
    float* tok_w     = (float*)(ws + WS_TOKW);
    unsigned short* xbf   = (unsigned short*)(ws + OFF_XBF);
    unsigned short* w13bf = (unsigned short*)(ws + OFF_W13);
    unsigned short* w2bf  = (unsigned short*)(ws + OFF_W2);
    unsigned short* act   = (unsigned short*)(ws + OFF_ACT);

    k_init<<<1, 64, 0, stream>>>(hdr);
    k_zero<<<(T_TOK * (long)H_DIM / 4 + 255) / 256, 256, 0, stream>>>((float4*)d_out, T_TOK * (long)H_DIM / 4);
    k_router<<<(T_TOK + 255) / 256, 256, 0, stream>>>(logits, hdr, tok_e, tok_w);
    k_offsets<<<1, 256, 0, stream>>>(hdr, slot_rows, slot_w);
    k_place<<<(T_TOK + 255) / 256, 256, 0, stream>>>(tok_e, tok_w, hdr, slot_rows, slot_w);

    long nx  = (long)T_TOK * H_DIM / 4;
    long n13 = (long)E_NUM * 2 * I_DIM * H_DIM / 4;
    long n2  = (long)E_NUM * H_DIM * I_DIM / 4;
    k_cvt<<<(nx  + 255) / 256, 256, 0, stream>>>((const float4*)x,   (us4*)xbf,   nx);
    k_cvt<<<(n13 + 255) / 256, 256, 0, stream>>>((const float4*)w13, (us4*)w13bf, n13);
    k_cvt<<<(n2  + 255) / 256, 256, 0, stream>>>((const float4*)w2,  (us4*)w2bf,  n2);

    k_gemm1<<<dim3(I_DIM / 128, SCAP / 128), 256, 0, stream>>>(xbf, w13bf, slot_rows, hdr, act);
    k_gemm2<<<dim3(H_DIM / 128, SCAP / 128), 256, 0, stream>>>(act, w2bf, slot_rows, slot_w, hdr, out);
}

// Round 4
// 2086.937 us; speedup vs baseline: 1.0299x; 1.0299x over previous
//
#include <hip/hip_runtime.h>
#include <stdint.h>

#define T_TOK 8192
#define H_DIM 2048
#define I_DIM 4096
#define E_NUM 8
#define SCAP (2*T_TOK + E_NUM*128)   // 17408 padded slot capacity

typedef short bf16x8 __attribute__((ext_vector_type(8)));
typedef float f32x4  __attribute__((ext_vector_type(4)));

typedef __attribute__((address_space(1))) void gvoid;
typedef __attribute__((address_space(3))) void svoid;

__device__ __forceinline__ void gl_lds16(const void* g, void* l) {
    // async global->LDS, 16B/lane; LDS dest = wave-uniform base + lane*16
    __builtin_amdgcn_global_load_lds((gvoid*)g, (svoid*)l, 16, 0, 0);
}

__device__ __forceinline__ unsigned short f2bf(float f) {
    union { float f; unsigned int u; } v; v.f = f;
    unsigned int u = v.u;
    unsigned int r = (u + 0x7fffu + ((u >> 16) & 1u)) >> 16;  // RNE
    return (unsigned short)r;
}

// ---- ws layout (bytes) ----
// hdr ints: [0..7]=counts [16..23]=cursors [32..40]=off[9] [48]=total
#define WS_ROWS   4096ULL
#define WS_SLOTW  (WS_ROWS + (unsigned long long)SCAP*4)
#define WS_TOKE   (WS_SLOTW + (unsigned long long)SCAP*4)
#define WS_TOKW   (WS_TOKE + 2ULL*T_TOK*4)
#define WS_TOKS   (WS_TOKW + 2ULL*T_TOK*4)
#define OFF_XBF   1048576ULL
#define OFF_W13   (OFF_XBF + 2ULL*T_TOK*H_DIM)
#define OFF_W2    (OFF_W13 + 2ULL*E_NUM*2*I_DIM*H_DIM)
#define OFF_ACT   (OFF_W2  + 2ULL*E_NUM*H_DIM*I_DIM)
// y (f32, SCAP x H_DIM = 142.6 MB) aliases the w13bf region (268 MB):
// w13bf is dead after k_gemm1; y is produced by k_gemm2 and consumed by
// k_combine, all stream-ordered, and re-created every launch. No extra ws.
#define OFF_Y     OFF_W13

struct us4 { unsigned short x, y, z, w; };

__global__ void k_init(int* hdr) {
    int i = threadIdx.x;
    if (i < 64) hdr[i] = 0;
}

__global__ void k_cvt(const float4* __restrict__ in, us4* __restrict__ out, long n4) {
    long i = (long)blockIdx.x * blockDim.x + threadIdx.x;
    if (i >= n4) return;
    float4 v = in[i];
    us4 o; o.x = f2bf(v.x); o.y = f2bf(v.y); o.z = f2bf(v.z); o.w = f2bf(v.w);
    out[i] = o;
}

__global__ void k_router(const float* __restrict__ logits, int* __restrict__ hdr,
                         int* __restrict__ tok_e, float* __restrict__ tok_w) {
    int t = blockIdx.x * blockDim.x + threadIdx.x;
    if (t >= T_TOK) return;
    float l[E_NUM];
    #pragma unroll
    for (int e = 0; e < E_NUM; e++) l[e] = logits[t * E_NUM + e];
    int i0 = 0; float m0 = l[0];
    #pragma unroll
    for (int e = 1; e < E_NUM; e++) if (l[e] > m0) { m0 = l[e]; i0 = e; }
    int i1 = -1; float m1 = -1e30f;
    #pragma unroll
    for (int e = 0; e < E_NUM; e++) if (e != i0 && l[e] > m1) { m1 = l[e]; i1 = e; }
    // normalized top-2 softmax weights == softmax over the two logits
    float p1 = expf(m1 - m0);
    float w0 = 1.f / (1.f + p1);
    float w1 = p1 * w0;
    tok_e[2*t] = i0; tok_e[2*t+1] = i1;
    tok_w[2*t] = w0; tok_w[2*t+1] = w1;
    atomicAdd(&hdr[i0], 1);
    atomicAdd(&hdr[i1], 1);
}

__global__ void k_offsets(int* hdr, int* slot_rows, float* slot_w) {
    if (threadIdx.x == 0) {
        int acc = 0;
        for (int e = 0; e < E_NUM; e++) {
            hdr[32 + e] = acc;
            int c = hdr[e];
            acc += (c + 127) & ~127;   // pad each expert region to 128 rows
        }
        hdr[32 + E_NUM] = acc;
        hdr[48] = acc;
    }
    for (int i = threadIdx.x; i < SCAP; i += blockDim.x) { slot_rows[i] = 0; slot_w[i] = 0.f; }
}

__global__ void k_place(const int* __restrict__ tok_e, const float* __restrict__ tok_w,
                        int* hdr, int* slot_rows, float* slot_w, int* __restrict__ tok_slot) {
    int t = blockIdx.x * blockDim.x + threadIdx.x;
    if (t >= T_TOK) return;
    #pragma unroll
    for (int k = 0; k < 2; k++) {
        int e = tok_e[2*t + k];
        float w = tok_w[2*t + k];
        int pos = atomicAdd(&hdr[16 + e], 1);
        int slot = hdr[32 + e] + pos;
        slot_rows[slot] = t;
        slot_w[slot] = w;
        tok_slot[2*t + k] = slot;
    }
}

// GEMM1: act[slot, i] = silu(x@w13g^T) * (x@w13u^T), bf16 out. 128x128 tile, BK=32.
// Double-buffered LDS: stage k+1 into buf^1 BEFORE compute on buf; ONE barrier/K-step.
__global__ __launch_bounds__(256, 2)
void k_gemm1(const unsigned short* __restrict__ xbf,
             const unsigned short* __restrict__ w13,
             const int* __restrict__ slot_rows,
             const int* __restrict__ hdr,
             unsigned short* __restrict__ act) {
    const int total = hdr[48];
    const int row0 = blockIdx.y * 128;
    if (row0 >= total) return;
    int e = 0;
    #pragma unroll
    for (int q = 0; q < E_NUM - 1; q++) if (row0 >= hdr[32 + q + 1]) e = q + 1;
    const int cb = blockIdx.x;   // 0..31 over gate columns (I/128)

    // 2 buffers x (A | G | U), each 128x32 bf16 = 8KB -> 48KB total
    __shared__ __align__(16) unsigned short lds[2 * 3 * 128 * 32];

    const int tid = threadIdx.x;
    const int wave = tid >> 6, lane = tid & 63;
    const int srow = lane >> 2, scol = (lane & 3) * 8;

    const unsigned short* aP[2]; const unsigned short* gP[2]; const unsigned short* uP[2];
    int lo[2];
    #pragma unroll
    for (int c = 0; c < 2; c++) {
        int r = c * 64 + wave * 16 + srow;          // 0..127 tile row
        int tok = slot_rows[row0 + r];
        aP[c] = xbf + (size_t)tok * H_DIM + scol;
        size_t n = (size_t)(cb * 128 + r);
        gP[c] = w13 + ((size_t)e * 2 * I_DIM + n) * H_DIM + scol;
        uP[c] = w13 + ((size_t)e * 2 * I_DIM + I_DIM + n) * H_DIM + scol;
        lo[c] = (c * 64 + wave * 16) * 32;          // wave-uniform LDS row offset (elems)
    }

    const int wm = wave >> 1, wn = wave & 1;
    const int fm = lane & 15, fk = (lane >> 4) * 8;

    f32x4 accg[4][4], accu[4][4];
    f32x4 zero = {0.f, 0.f, 0.f, 0.f};
    #pragma unroll
    for (int i = 0; i < 4; i++)
        #pragma unroll
        for (int j = 0; j < 4; j++) { accg[i][j] = zero; accu[i][j] = zero; }

#define G1_STAGE(BUF, KO) do {                                   \
        unsigned short* _p = lds + (BUF) * 12288;                \
        _Pragma("unroll")                                        \
        for (int c = 0; c < 2; c++) {                            \
            gl_lds16(aP[c] + (KO), _p + lo[c]);                  \
            gl_lds16(gP[c] + (KO), _p + 4096 + lo[c]);           \
            gl_lds16(uP[c] + (KO), _p + 8192 + lo[c]);           \
        }                                                        \
    } while (0)

    G1_STAGE(0, 0);
    __syncthreads();              // drains vmcnt -> buf0 ready
    int cur = 0;

    for (int k0 = 0; k0 < H_DIM; k0 += 32) {
        if (k0 + 32 < H_DIM) G1_STAGE(cur ^ 1, k0 + 32);   // prefetch overlaps compute

        const unsigned short* ldsA = lds + cur * 12288;
        const unsigned short* ldsG = ldsA + 4096;
        const unsigned short* ldsU = ldsA + 8192;

        bf16x8 a[4], bg[4], bu[4];
        #pragma unroll
        for (int i = 0; i < 4; i++) a[i] = *(const bf16x8*)&ldsA[(wm * 64 + i * 16 + fm) * 32 + fk];
        #pragma unroll
        for (int j = 0; j < 4; j++) {
            bg[j] = *(const bf16x8*)&ldsG[(wn * 64 + j * 16 + fm) * 32 + fk];
            bu[j] = *(const bf16x8*)&ldsU[(wn * 64 + j * 16 + fm) * 32 + fk];
        }
        #pragma unroll
        for (int i = 0; i < 4; i++)
            #pragma unroll
            for (int j = 0; j < 4; j++) {
                accg[i][j] = __builtin_amdgcn_mfma_f32_16x16x32_bf16(a[i], bg[j], accg[i][j], 0, 0, 0);
                accu[i][j] = __builtin_amdgcn_mfma_f32_16x16x32_bf16(a[i], bu[j], accu[i][j], 0, 0, 0);
            }

        __syncthreads();          // drains lgkmcnt (reads done) + vmcnt (prefetch landed)
        cur ^= 1;
    }
#undef G1_STAGE

    const int r4 = (lane >> 4) * 4;
    #pragma unroll
    for (int i = 0; i < 4; i++) {
        #pragma unroll
        for (int j = 0; j < 4; j++) {
            int col = cb * 128 + wn * 64 + j * 16 + fm;
            #pragma unroll
            for (int r = 0; r < 4; r++) {
                int slot = row0 + wm * 64 + i * 16 + r4 + r;
                float g = accg[i][j][r], u = accu[i][j][r];
                float s = g / (1.f + __expf(-g)) * u;   // silu(g)*u
                act[(size_t)slot * I_DIM + col] = f2bf(s);
            }
        }
    }
}

// GEMM2: y[slot] = w * (act @ w2^T), plain f32 stores (no atomics).
// Same double-buffered single-barrier schedule.
__global__ __launch_bounds__(256, 2)
void k_gemm2(const unsigned short* __restrict__ act,
             const unsigned short* __restrict__ w2,
             const float* __restrict__ slot_w,
             const int* __restrict__ hdr,
             float* __restrict__ y) {
    const int total = hdr[48];
    const int row0 = blockIdx.y * 128;
    if (row0 >= total) return;
    int e = 0;
    #pragma unroll
    for (int q = 0; q < E_NUM - 1; q++) if (row0 >= hdr[32 + q + 1]) e = q + 1;
    const int cb = blockIdx.x;   // 0..15 over H/128

    // 2 buffers x (A | B), each 128x32 bf16 = 8KB -> 32KB total
    __shared__ __align__(16) unsigned short lds[2 * 2 * 128 * 32];

    const int tid = threadIdx.x;
    const int wave = tid >> 6, lane = tid & 63;
    const int srow = lane >> 2, scol = (lane & 3) * 8;

    const unsigned short* aP[2]; const unsigned short* bP[2];
    int lo[2];
    #pragma unroll
    for (int c = 0; c < 2; c++) {
        int r = c * 64 + wave * 16 + srow;
        aP[c] = act + (size_t)(row0 + r) * I_DIM + scol;
        size_t n = (size_t)(cb * 128 + r);
        bP[c] = w2 + ((size_t)e * H_DIM + n) * I_DIM + scol;
        lo[c] = (c * 64 + wave * 16) * 32;
    }

    const int wm = wave >> 1, wn = wave & 1;
    const int fm = lane & 15, fk = (lane >> 4) * 8;

    f32x4 acc[4][4];
    f32x4 zero = {0.f, 0.f, 0.f, 0.f};
    #pragma unroll
    for (int i = 0; i < 4; i++)
        #pragma unroll
        for (int j = 0; j < 4; j++) acc[i][j] = zero;

#define G2_STAGE(BUF, KO) do {                                   \
        unsigned short* _p = lds + (BUF) * 8192;                 \
        _Pragma("unroll")                                        \
        for (int c = 0; c < 2; c++) {                            \
            gl_lds16(aP[c] + (KO), _p + lo[c]);                  \
            gl_lds16(bP[c] + (KO), _p + 4096 + lo[c]);           \
        }                                                        \
    } while (0)

    G2_STAGE(0, 0);
    __syncthreads();
    int cur = 0;

    for (int k0 = 0; k0 < I_DIM; k0 += 32) {
        if (k0 + 32 < I_DIM) G2_STAGE(cur ^ 1, k0 + 32);

        const unsigned short* ldsA = lds + cur * 8192;
        const unsigned short* ldsB = ldsA + 4096;

        bf16x8 a[4], b[4];
        #pragma unroll
        for (int i = 0; i < 4; i++) a[i] = *(const bf16x8*)&ldsA[(wm * 64 + i * 16 + fm) * 32 + fk];
        #pragma unroll
        for (int j = 0; j < 4; j++) b[j] = *(const bf16x8*)&ldsB[(wn * 64 + j * 16 + fm) * 32 + fk];
        #pragma unroll
        for (int i = 0; i < 4; i++)
            #pragma unroll
            for (int j = 0; j < 4; j++)
                acc[i][j] = __builtin_amdgcn_mfma_f32_16x16x32_bf16(a[i], b[j], acc[i][j], 0, 0, 0);

        __syncthreads();
        cur ^= 1;
    }
#undef G2_STAGE

    const int r4 = (lane >> 4) * 4;
    float ww[16];
    #pragma unroll
    for (int i = 0; i < 4; i++)
        #pragma unroll
        for (int r = 0; r < 4; r++)
            ww[i * 4 + r] = slot_w[row0 + wm * 64 + i * 16 + r4 + r];
    #pragma unroll
    for (int i = 0; i < 4; i++) {
        #pragma unroll
        for (int j = 0; j < 4; j++) {
            int col = cb * 128 + wn * 64 + j * 16 + fm;
            #pragma unroll
            for (int r = 0; r < 4; r++) {
                int slot = row0 + wm * 64 + i * 16 + r4 + r;
                y[(size_t)slot * H_DIM + col] = ww[i * 4 + r] * acc[i][j][r];
            }
        }
    }
}

// combine: out[t] = y[slot0(t)] + y[slot1(t)]  (weights already applied in gemm2)
__global__ void k_combine(const float4* __restrict__ y4,
                          const int* __restrict__ tok_slot,
                          float4* __restrict__ out) {
    const long n4 = (long)T_TOK * (H_DIM / 4);
    long i = (long)blockIdx.x * blockDim.x + threadIdx.x;
    if (i >= n4) return;
    int t  = (int)(i >> 9);            // / (H_DIM/4 = 512)
    int c4 = (int)(i & 511);
    int s0 = tok_slot[2 * t], s1 = tok_slot[2 * t + 1];
    float4 a = y4[(long)s0 * (H_DIM / 4) + c4];
    float4 b = y4[(long)s1 * (H_DIM / 4) + c4];
    out[i] = make_float4(a.x + b.x, a.y + b.y, a.z + b.z, a.w + b.w);
}

extern "C" void kernel_launch(void* const* d_in, const int* in_sizes, int n_in,
                              void* d_out, int out_size, void* d_ws, size_t ws_size,
                              hipStream_t stream) {
    const float* x      = (const float*)d_in[0];
    const float* logits = (const float*)d_in[1];
    const float* w13    = (const float*)d_in[2];
    const float* w2     = (const float*)d_in[3];
    float* out = (float*)d_out;
    char* ws = (char*)d_ws;

    int*   hdr       = (int*)ws;
    int*   slot_rows = (int*)(ws + WS_ROWS);
    float* slot_w    = (float*)(ws + WS_SLOTW);
    int*   tok_e     = (int*)(ws + WS_TOKE);
    float* tok_w     = (float*)(ws + WS_TOKW);
    int*   tok_slot  = (int*)(ws + WS_TOKS);
    unsigned short* xbf   = (unsigned short*)(ws + OFF_XBF);
    unsigned short* w13bf = (unsigned short*)(ws + OFF_W13);
    unsigned short* w2bf  = (unsigned short*)(ws + OFF_W2);
    unsigned short* act   = (unsigned short*)(ws + OFF_ACT);
    float*          ybuf  = (float*)(ws + OFF_Y);   // aliases w13bf (dead after gemm1)

    k_init<<<1, 64, 0, stream>>>(hdr);
    k_router<<<(T_TOK + 255) / 256, 256, 0, stream>>>(logits, hdr, tok_e, tok_w);
    k_offsets<<<1, 256, 0, stream>>>(hdr, slot_rows, slot_w);
    k_place<<<(T_TOK + 255) / 256, 256, 0, stream>>>(tok_e, tok_w, hdr, slot_rows, slot_w, tok_slot);

    long nx  = (long)T_TOK * H_DIM / 4;
    long n13 = (long)E_NUM * 2 * I_DIM * H_DIM / 4;
    long n2  = (long)E_NUM * H_DIM * I_DIM / 4;
    k_cvt<<<(nx  + 255) / 256, 256, 0, stream>>>((const float4*)x,   (us4*)xbf,   nx);
    k_cvt<<<(n13 + 255) / 256, 256, 0, stream>>>((const float4*)w13, (us4*)w13bf, n13);
    k_cvt<<<(n2  + 255) / 256, 256, 0, stream>>>((const float4*)w2,  (us4*)w2bf,  n2);

    k_gemm1<<<dim3(I_DIM / 128, SCAP / 128), 256, 0, stream>>>(xbf, w13bf, slot_rows, hdr, act);
    k_gemm2<<<dim3(H_DIM / 128, SCAP / 128), 256, 0, stream>>>(act, w2bf, slot_w, hdr, ybuf);

    long nc = (long)T_TOK * (H_DIM / 4);
    k_combine<<<(int)((nc + 255) / 256), 256, 0, stream>>>((const float4*)ybuf, tok_slot, (float4*)out);
}